// Round 4
// baseline (502.154 us; speedup 1.0000x reference)
//
#include <hip/hip_runtime.h>
#include <math.h>

#define Bn 32
#define Nn 2000
#define En 32000
#define Vn 100000
#define Dn 128
#define Rn 39
#define Kn 8

#define HALF (Nn / 2)     // 1000 dst nodes per cnt block
#define CH 64             // gather chunks per graph

// Workspace layout (bytes):
//   [0)         : cnt     u16  [B*N*R]        = 4,992,000  (dead after K2)
//   [0)         : partial float[B*CH*9*128]   = 9,437,184  (aliases cnt, written in K3)
//   [9,984,000) : a       float[B*N*K]        = 2,048,000
// total 12,032,000 bytes (same as R1/R2 layout)
//
// Grid swizzle: graph index is blockIdx.x so all blocks of graph b have
// linear id == b (mod 8) -> same XCD -> graph-local data stays in 4MB L2.

// K1: 2 blocks per graph, each owns dst-range [s0, s0+1000). Whole-range u16
// histogram packed 2-per-u32 in LDS (78 KB), single scan, direct store.
__global__ __launch_bounds__(1024) void cnt_kernel(const int* __restrict__ edge_index,
                                                   const int* __restrict__ edge_type,
                                                   unsigned short* __restrict__ cnt) {
    int b = blockIdx.x, half = blockIdx.y;
    int s0 = half * HALF;
    __shared__ unsigned int loc[HALF * Rn / 2];   // 19500 words = 78 KB
    for (int i = threadIdx.x; i < HALF * Rn / 2; i += 1024) loc[i] = 0u;
    __syncthreads();
    const int* dstp = edge_index + (b * 2 + 1) * En;
    const int* etp  = edge_type + b * En;
    for (int e = threadIdx.x; e < En; e += 1024) {
        int du = dstp[e] - s0;
        if ((unsigned)du < HALF) {
            int idx = du * Rn + etp[e];
            atomicAdd(&loc[idx >> 1], 1u << ((idx & 1) * 16));
        }
    }
    __syncthreads();
    unsigned int* g = (unsigned int*)(cnt + (size_t)b * Nn * Rn + s0 * Rn);
    for (int i = threadIdx.x; i < HALF * Rn / 2; i += 1024) g[i] = loc[i];
}

// K2: 1 block per graph owns the whole src range. a_loc padded to stride 9
// (coprime with 32 banks -> no 4-bank aliasing like stride 8 had in R2).
__global__ __launch_bounds__(1024) void a_kernel(const int* __restrict__ edge_index,
                                                 const int* __restrict__ edge_type,
                                                 const unsigned short* __restrict__ cnt,
                                                 const float* __restrict__ comp,
                                                 float* __restrict__ a) {
    int b = blockIdx.x;
    __shared__ float loc[Nn * 9];                 // 72 KB
    __shared__ float comp_l[Rn * Kn];
    for (int i = threadIdx.x; i < Nn * 9; i += 1024) loc[i] = 0.0f;
    for (int i = threadIdx.x; i < Rn * Kn; i += 1024) comp_l[i] = comp[i];
    __syncthreads();
    const int* srcp = edge_index + (b * 2 + 0) * En;
    const int* dstp = edge_index + (b * 2 + 1) * En;
    const int* etp  = edge_type + b * En;
    const unsigned short* cb = cnt + (size_t)b * Nn * Rn;
    for (int e = threadIdx.x; e < En; e += 1024) {
        int src = srcp[e];
        int dst = dstp[e];
        int t   = etp[e];
        float inv = 1.0f / (float)cb[dst * Rn + t];
        float* lrow = &loc[src * 9];
        const float* crow = &comp_l[t * Kn];
#pragma unroll
        for (int k = 0; k < Kn; k++) atomicAdd(&lrow[k], crow[k] * inv);  // LDS atomic
    }
    __syncthreads();
    float* g = a + (size_t)b * Nn * Kn;
    for (int i = threadIdx.x; i < Nn * Kn; i += 1024) {
        int n = i >> 3, k = i & 7;
        g[i] = loc[n * 9 + k];
    }
}

// K3: gather embedding rows; 9 register accumulators; block-local LDS combine;
// non-atomic partial store per chunk.
__global__ __launch_bounds__(256) void gather_kernel(const int* __restrict__ node_ids,
                                                     const float* __restrict__ emb,
                                                     const float* __restrict__ a,
                                                     float* __restrict__ partial) {
    int b = blockIdx.x, c = blockIdx.y;
    int d = threadIdx.x & (Dn - 1);
    int w = threadIdx.x >> 7;                     // 2 node-workers per block
    float acc[9];
#pragma unroll
    for (int k = 0; k < 9; k++) acc[k] = 0.0f;
    for (int n = c * 2 + w; n < Nn; n += CH * 2) {
        int nid = node_ids[b * Nn + n];
        float v = emb[(size_t)nid * Dn + d];      // coalesced 512B row
        const float4* ar = (const float4*)(a + (size_t)(b * Nn + n) * Kn);
        float4 a0 = ar[0], a1 = ar[1];
        acc[8] += v;
        acc[0] += a0.x * v; acc[1] += a0.y * v; acc[2] += a0.z * v; acc[3] += a0.w * v;
        acc[4] += a1.x * v; acc[5] += a1.y * v; acc[6] += a1.z * v; acc[7] += a1.w * v;
    }
    __shared__ float red[9 * Dn];
    if (w == 0) {
#pragma unroll
        for (int k = 0; k < 9; k++) red[k * Dn + d] = acc[k];
    }
    __syncthreads();
    if (w == 1) {
#pragma unroll
        for (int k = 0; k < 9; k++) red[k * Dn + d] += acc[k];
    }
    __syncthreads();
    float* g = partial + ((size_t)b * CH + c) * 9 * Dn;
    for (int i = threadIdx.x; i < 9 * Dn; i += 256) g[i] = red[i];
}

// K4: reduce chunk partials, 9x(128x128) matvec split across 2 thread-halves,
// L2-normalize.
__global__ __launch_bounds__(256) void final_kernel(const float* __restrict__ partial,
                                                    const float* __restrict__ root,
                                                    const float* __restrict__ bases,
                                                    const float* __restrict__ bias,
                                                    float* __restrict__ out) {
    int b = blockIdx.x;
    int d = threadIdx.x & (Dn - 1);
    int h = threadIdx.x >> 7;                     // 0 or 1
    __shared__ float ts[9 * Dn];
    for (int i = threadIdx.x; i < 9 * Dn; i += 256) {
        float s = 0.0f;
        const float* p = partial + (size_t)b * CH * 9 * Dn + i;
        for (int c = 0; c < CH; c++) s += p[c * 9 * Dn];
        ts[i] = s;
    }
    __syncthreads();
    float gp = 0.0f;
    if (h == 0) {
        const float* sv = &ts[8 * Dn];
        for (int j = 0; j < Dn; j++) gp += sv[j] * root[j * Dn + d];
        for (int k = 0; k < 4; k++) {
            const float* Bk = bases + (size_t)k * Dn * Dn;
            const float* tk = &ts[k * Dn];
            for (int j = 0; j < Dn; j++) gp += tk[j] * Bk[j * Dn + d];
        }
    } else {
        for (int k = 4; k < Kn; k++) {
            const float* Bk = bases + (size_t)k * Dn * Dn;
            const float* tk = &ts[k * Dn];
            for (int j = 0; j < Dn; j++) gp += tk[j] * Bk[j * Dn + d];
        }
    }
    __shared__ float gsh[2][Dn];
    gsh[h][d] = gp;
    __syncthreads();
    float g = 0.0f;
    if (h == 0) g = (float)Nn * bias[d] + gsh[0][d] + gsh[1][d];
    float ss = g * g;                              // h==1 lanes contribute 0
#pragma unroll
    for (int off = 32; off > 0; off >>= 1) ss += __shfl_down(ss, off, 64);
    __shared__ float s4[4];
    if ((threadIdx.x & 63) == 0) s4[threadIdx.x >> 6] = ss;
    __syncthreads();
    float nrm = sqrtf(s4[0] + s4[1] + s4[2] + s4[3]);
    if (h == 0) out[b * Dn + d] = g / fmaxf(nrm, 1e-5f);
}

extern "C" void kernel_launch(void* const* d_in, const int* in_sizes, int n_in,
                              void* d_out, int out_size, void* d_ws, size_t ws_size,
                              hipStream_t stream) {
    const int*   node_ids   = (const int*)d_in[0];
    const int*   edge_index = (const int*)d_in[1];
    const int*   edge_type  = (const int*)d_in[2];
    const float* embedding  = (const float*)d_in[3];
    const float* bases      = (const float*)d_in[4];
    const float* comp       = (const float*)d_in[5];
    const float* root       = (const float*)d_in[6];
    const float* bias       = (const float*)d_in[7];
    float*       out        = (float*)d_out;

    unsigned short* cnt     = (unsigned short*)d_ws;              // dead after K2
    float*          partial = (float*)d_ws;                       // aliases cnt (K3+)
    float*          a       = (float*)((char*)d_ws + 9984000);

    cnt_kernel   <<<dim3(Bn, 2),  1024, 0, stream>>>(edge_index, edge_type, cnt);
    a_kernel     <<<Bn,           1024, 0, stream>>>(edge_index, edge_type, cnt, comp, a);
    gather_kernel<<<dim3(Bn, CH), 256,  0, stream>>>(node_ids, embedding, a, partial);
    final_kernel <<<Bn, 256, 0, stream>>>(partial, root, bases, bias, out);
}

// Round 5
// 175.529 us; speedup vs baseline: 2.8608x; 2.8608x over previous
//
#include <hip/hip_runtime.h>
#include <math.h>

#define Bn 32
#define Nn 2000
#define En 32000
#define Vn 100000
#define Dn 128
#define Rn 39
#define Kn 8

#define SUBS 16
#define NPS (Nn / SUBS)   // 125 nodes per sub-block
#define CH 64             // gather chunks per graph

// Workspace layout (bytes):
//   [0)         : cnt     int  [B*N*R]      = 9,984,000  (dead after a_kernel)
//   [0)         : partial float[B*CH*9*128] = 9,437,184  (aliases cnt; gather writes)
//   [9,984,000) : a       float[B*N*K]      = 2,048,000  (dead after gather)
//   [9,984,000) : gmat    float[B*9*128]    =   147,456  (aliases a; matvec writes)
// total 12,032,000 bytes (proven size)
//
// blockIdx.x = graph everywhere -> all blocks of graph b share (b mod 8) XCD
// -> graph-local edge data stays in that XCD's L2 (R2 evidence: 9x fetch cut).

// K1: 16 blocks/graph, each owns dst-range [s0,s0+125). 19.5KB LDS histogram
// -> 2 blocks/CU (2048 threads, full capacity). Unroll-2 scan for MLP.
__global__ __launch_bounds__(1024) void cnt_kernel(const int* __restrict__ edge_index,
                                                   const int* __restrict__ edge_type,
                                                   int* __restrict__ cnt) {
    int b = blockIdx.x, sub = blockIdx.y;
    int s0 = sub * NPS;
    __shared__ int loc[NPS * Rn];                 // 4875 ints = 19.5 KB
    for (int i = threadIdx.x; i < NPS * Rn; i += 1024) loc[i] = 0;
    __syncthreads();
    const int* dstp = edge_index + (b * 2 + 1) * En;
    const int* etp  = edge_type + b * En;
    for (int e = threadIdx.x; e < En; e += 2048) {
        int du0 = dstp[e] - s0;
        int e1 = e + 1024;
        int du1 = (e1 < En) ? (dstp[e1] - s0) : -1;
        if ((unsigned)du0 < NPS) atomicAdd(&loc[du0 * Rn + etp[e]], 1);
        if ((unsigned)du1 < NPS) atomicAdd(&loc[du1 * Rn + etp[e1]], 1);
    }
    __syncthreads();
    int* g = cnt + ((size_t)b * Nn + s0) * Rn;
    for (int i = threadIdx.x; i < NPS * Rn; i += 1024) g[i] = loc[i];
}

// K2: 16 blocks/graph own src-ranges. ONE LDS atomic per edge into
// s[src][t] (stride 39, coprime to 32 banks), then a[n][k] = s @ comp.
__global__ __launch_bounds__(1024) void a_kernel(const int* __restrict__ edge_index,
                                                 const int* __restrict__ edge_type,
                                                 const int* __restrict__ cnt,
                                                 const float* __restrict__ comp,
                                                 float* __restrict__ a) {
    int b = blockIdx.x, sub = blockIdx.y;
    int s0 = sub * NPS;
    __shared__ float s[NPS * Rn];                 // 4875 floats = 19.5 KB
    __shared__ float comp_l[Rn * Kn];
    for (int i = threadIdx.x; i < NPS * Rn; i += 1024) s[i] = 0.0f;
    if (threadIdx.x < Rn * Kn) comp_l[threadIdx.x] = comp[threadIdx.x];
    __syncthreads();
    const int* srcp = edge_index + (b * 2 + 0) * En;
    const int* dstp = edge_index + (b * 2 + 1) * En;
    const int* etp  = edge_type + b * En;
    const int* cb   = cnt + (size_t)b * Nn * Rn;
    for (int e = threadIdx.x; e < En; e += 2048) {
        int su0 = srcp[e] - s0;
        int e1 = e + 1024;
        int su1 = (e1 < En) ? (srcp[e1] - s0) : -1;
        if ((unsigned)su0 < NPS) {
            int t = etp[e];
            float inv = 1.0f / (float)cb[dstp[e] * Rn + t];
            atomicAdd(&s[su0 * Rn + t], inv);
        }
        if ((unsigned)su1 < NPS) {
            int t = etp[e1];
            float inv = 1.0f / (float)cb[dstp[e1] * Rn + t];
            atomicAdd(&s[su1 * Rn + t], inv);
        }
    }
    __syncthreads();
    float* g = a + ((size_t)b * Nn + s0) * Kn;
    for (int i = threadIdx.x; i < NPS * Kn; i += 1024) {   // 1000 outputs
        int n = i >> 3, k = i & 7;
        float acc = 0.0f;
        const float* srow = &s[n * Rn];
        for (int t = 0; t < Rn; t++) acc += srow[t] * comp_l[t * Kn + k];
        g[i] = acc;
    }
}

// K3: wave-autonomous gather: each wave loads a FULL 512B embedding row per
// instruction (float2/lane). Unroll-2 nodes. 4-wave LDS combine, direct store.
__global__ __launch_bounds__(256) void gather_kernel(const int* __restrict__ node_ids,
                                                     const float* __restrict__ emb,
                                                     const float* __restrict__ a,
                                                     float* __restrict__ partial) {
    int b = blockIdx.x, c = blockIdx.y;
    int lane = threadIdx.x & 63, wv = threadIdx.x >> 6;   // 4 waves
    float acc[18];
#pragma unroll
    for (int k = 0; k < 18; k++) acc[k] = 0.0f;
    const int* nb = node_ids + b * Nn;
    for (int n = c * 4 + wv; n < Nn; n += 2 * CH * 4) {   // nodes n, n+256
        int n2 = n + CH * 4;
        bool has2 = n2 < Nn;
        int nid  = nb[n];
        int nid2 = has2 ? nb[n2] : 0;
        float2 v  = ((const float2*)(emb + (size_t)nid  * Dn))[lane];
        float2 v2 = has2 ? ((const float2*)(emb + (size_t)nid2 * Dn))[lane]
                         : make_float2(0.f, 0.f);
        const float4* ar = (const float4*)(a + ((size_t)b * Nn + n) * Kn);
        float4 a0 = ar[0], a1 = ar[1];
        float w[9] = {a0.x, a0.y, a0.z, a0.w, a1.x, a1.y, a1.z, a1.w, 1.0f};
#pragma unroll
        for (int k = 0; k < 9; k++) { acc[2*k] += w[k] * v.x; acc[2*k+1] += w[k] * v.y; }
        if (has2) {
            const float4* ar2 = (const float4*)(a + ((size_t)b * Nn + n2) * Kn);
            float4 b0 = ar2[0], b1 = ar2[1];
            float w2[9] = {b0.x, b0.y, b0.z, b0.w, b1.x, b1.y, b1.z, b1.w, 1.0f};
#pragma unroll
            for (int k = 0; k < 9; k++) { acc[2*k] += w2[k] * v2.x; acc[2*k+1] += w2[k] * v2.y; }
        }
    }
    __shared__ float red[4 * 9 * Dn];             // 18 KB
#pragma unroll
    for (int k = 0; k < 9; k++) {
        ((float2*)&red[(wv * 9 + k) * Dn])[lane] = make_float2(acc[2*k], acc[2*k+1]);
    }
    __syncthreads();
    float* g = partial + ((size_t)b * CH + c) * 9 * Dn;
    for (int i = threadIdx.x; i < 9 * Dn; i += 256)
        g[i] = red[i] + red[9 * Dn + i] + red[18 * Dn + i] + red[27 * Dn + i];
}

// K4a: one block per (graph, matrix m). m<8 -> bases[m] @ t_m ; m==8 -> root @ s.
__global__ __launch_bounds__(256) void matvec_kernel(const float* __restrict__ partial,
                                                     const float* __restrict__ root,
                                                     const float* __restrict__ bases,
                                                     float* __restrict__ gmat) {
    int b = blockIdx.x, m = blockIdx.y;
    int d = threadIdx.x & (Dn - 1), h = threadIdx.x >> 7;
    __shared__ float ts[Dn];
    __shared__ float tsh[2][Dn];
    const float* p = partial + (size_t)b * CH * 9 * Dn + m * Dn + d;
    float sum = 0.0f;
    for (int c = h; c < CH; c += 2) sum += p[(size_t)c * 9 * Dn];
    tsh[h][d] = sum;
    __syncthreads();
    if (h == 0) ts[d] = tsh[0][d] + tsh[1][d];
    __syncthreads();
    const float* M = (m == 8) ? root : bases + (size_t)m * Dn * Dn;
    float g = 0.0f;
    for (int j = h * 64; j < h * 64 + 64; j++) g += ts[j] * M[j * Dn + d];
    __syncthreads();
    tsh[h][d] = g;
    __syncthreads();
    if (h == 0) gmat[((size_t)b * 9 + m) * Dn + d] = tsh[0][d] + tsh[1][d];
}

// K4b: sum the 9 matvec outputs, add bias term, L2-normalize.
__global__ __launch_bounds__(128) void norm_kernel(const float* __restrict__ gmat,
                                                   const float* __restrict__ bias,
                                                   float* __restrict__ out) {
    int b = blockIdx.x, d = threadIdx.x;
    float g = (float)Nn * bias[d];
    const float* gb = gmat + (size_t)b * 9 * Dn + d;
#pragma unroll
    for (int m = 0; m < 9; m++) g += gb[m * Dn];
    float ss = g * g;
#pragma unroll
    for (int off = 32; off > 0; off >>= 1) ss += __shfl_down(ss, off, 64);
    __shared__ float s2[2];
    if ((threadIdx.x & 63) == 0) s2[threadIdx.x >> 6] = ss;
    __syncthreads();
    float nrm = sqrtf(s2[0] + s2[1]);
    out[b * Dn + d] = g / fmaxf(nrm, 1e-5f);
}

extern "C" void kernel_launch(void* const* d_in, const int* in_sizes, int n_in,
                              void* d_out, int out_size, void* d_ws, size_t ws_size,
                              hipStream_t stream) {
    const int*   node_ids   = (const int*)d_in[0];
    const int*   edge_index = (const int*)d_in[1];
    const int*   edge_type  = (const int*)d_in[2];
    const float* embedding  = (const float*)d_in[3];
    const float* bases      = (const float*)d_in[4];
    const float* comp       = (const float*)d_in[5];
    const float* root       = (const float*)d_in[6];
    const float* bias       = (const float*)d_in[7];
    float*       out        = (float*)d_out;

    int*   cnt     = (int*)d_ws;                         // dead after a_kernel
    float* partial = (float*)d_ws;                       // aliases cnt
    float* a       = (float*)((char*)d_ws + 9984000);    // dead after gather
    float* gmat    = a;                                  // aliases a

    cnt_kernel   <<<dim3(Bn, SUBS), 1024, 0, stream>>>(edge_index, edge_type, cnt);
    a_kernel     <<<dim3(Bn, SUBS), 1024, 0, stream>>>(edge_index, edge_type, cnt, comp, a);
    gather_kernel<<<dim3(Bn, CH),   256,  0, stream>>>(node_ids, embedding, a, partial);
    matvec_kernel<<<dim3(Bn, 9),    256,  0, stream>>>(partial, root, bases, gmat);
    norm_kernel  <<<Bn, 128, 0, stream>>>(gmat, bias, out);
}

// Round 6
// 166.676 us; speedup vs baseline: 3.0128x; 1.0531x over previous
//
#include <hip/hip_runtime.h>
#include <math.h>

#define Bn 32
#define Nn 2000
#define En 32000
#define Vn 100000
#define Dn 128
#define Rn 39
#define Kn 8

#define SUBS 8
#define NPS (Nn / SUBS)   // 250 nodes per sub-block
#define CH 128            // gather chunks per graph
#define EQ (En / 4)       // 8000 edge-quads per graph

// Workspace layout (ws_size = 256 MiB per the harness fill; no aliasing):
//   [ 0)          : cnt     int  [B*N*R]       =  9,984,000
//   [ 9,984,000)  : inv     float[B*E]         =  4,096,000
//   [14,080,000)  : a       float[B*N*K]       =  2,048,000
//   [16,128,000)  : partial float[B*CH*9*128]  = 18,874,368
//   [35,002,368+] : gmat    float[B*9*128]     =    147,456   (at 35,004,416)
//
// blockIdx.x = graph everywhere -> all blocks of graph b share (b mod 8) XCD
// -> graph-local edge/cnt data stays in that XCD's L2 (R2 evidence: 9x fetch cut).

// K1: 8 blocks/graph, each owns dst-range [s0,s0+250). int4 scan (4 edges/iter).
__global__ __launch_bounds__(1024) void cnt_kernel(const int* __restrict__ edge_index,
                                                   const int* __restrict__ edge_type,
                                                   int* __restrict__ cnt) {
    int b = blockIdx.x, sub = blockIdx.y;
    int s0 = sub * NPS;
    __shared__ int loc[NPS * Rn];                 // 9750 ints = 39 KB
    for (int i = threadIdx.x; i < NPS * Rn; i += 1024) loc[i] = 0;
    __syncthreads();
    const int4* dst4 = (const int4*)(edge_index + (b * 2 + 1) * En);
    const int4* et4  = (const int4*)(edge_type + b * En);
    for (int q = threadIdx.x; q < EQ; q += 1024) {
        int4 d = dst4[q];
        int4 t = et4[q];
        int x;
        x = d.x - s0; if ((unsigned)x < NPS) atomicAdd(&loc[x * Rn + t.x], 1);
        x = d.y - s0; if ((unsigned)x < NPS) atomicAdd(&loc[x * Rn + t.y], 1);
        x = d.z - s0; if ((unsigned)x < NPS) atomicAdd(&loc[x * Rn + t.z], 1);
        x = d.w - s0; if ((unsigned)x < NPS) atomicAdd(&loc[x * Rn + t.w], 1);
    }
    __syncthreads();
    int* g = cnt + ((size_t)b * Nn + s0) * Rn;
    for (int i = threadIdx.x; i < NPS * Rn; i += 1024) g[i] = loc[i];
}

// K2: edge-parallel inv[b][e] = 1/cnt[dst,et]. One random L2 lookup per edge,
// done ONCE (not 8x inside the redundant a-scan).
__global__ __launch_bounds__(256) void inv_kernel(const int* __restrict__ edge_index,
                                                  const int* __restrict__ edge_type,
                                                  const int* __restrict__ cnt,
                                                  float* __restrict__ inv) {
    int b = blockIdx.x;
    int q = blockIdx.y * 256 + threadIdx.x;       // quad index
    if (q >= EQ) return;
    int4 d = ((const int4*)(edge_index + (b * 2 + 1) * En))[q];
    int4 t = ((const int4*)(edge_type + b * En))[q];
    const int* cb = cnt + (size_t)b * Nn * Rn;
    float4 r;
    r.x = 1.0f / (float)cb[d.x * Rn + t.x];
    r.y = 1.0f / (float)cb[d.y * Rn + t.y];
    r.z = 1.0f / (float)cb[d.z * Rn + t.z];
    r.w = 1.0f / (float)cb[d.w * Rn + t.w];
    ((float4*)(inv + (size_t)b * En))[q] = r;
}

// K3: 8 blocks/graph own src-ranges. Pure streaming scan (src,et,inv all
// sequential), ONE LDS atomic/edge into s[src][t] (stride 39, coprime to 32
// banks), then a[n][k] = s @ comp.
__global__ __launch_bounds__(1024) void a_kernel(const int* __restrict__ edge_index,
                                                 const int* __restrict__ edge_type,
                                                 const float* __restrict__ inv,
                                                 const float* __restrict__ comp,
                                                 float* __restrict__ a) {
    int b = blockIdx.x, sub = blockIdx.y;
    int s0 = sub * NPS;
    __shared__ float s[NPS * Rn];                 // 9750 floats = 39 KB
    __shared__ float comp_l[Rn * Kn];
    for (int i = threadIdx.x; i < NPS * Rn; i += 1024) s[i] = 0.0f;
    if (threadIdx.x < Rn * Kn) comp_l[threadIdx.x] = comp[threadIdx.x];
    __syncthreads();
    const int4*   src4 = (const int4*)(edge_index + (b * 2 + 0) * En);
    const int4*   et4  = (const int4*)(edge_type + b * En);
    const float4* iv4  = (const float4*)(inv + (size_t)b * En);
    for (int q = threadIdx.x; q < EQ; q += 1024) {
        int4 sv = src4[q];
        int4 tv = et4[q];
        float4 iv = iv4[q];
        int x;
        x = sv.x - s0; if ((unsigned)x < NPS) atomicAdd(&s[x * Rn + tv.x], iv.x);
        x = sv.y - s0; if ((unsigned)x < NPS) atomicAdd(&s[x * Rn + tv.y], iv.y);
        x = sv.z - s0; if ((unsigned)x < NPS) atomicAdd(&s[x * Rn + tv.z], iv.z);
        x = sv.w - s0; if ((unsigned)x < NPS) atomicAdd(&s[x * Rn + tv.w], iv.w);
    }
    __syncthreads();
    float* g = a + ((size_t)b * Nn + s0) * Kn;
    for (int i = threadIdx.x; i < NPS * Kn; i += 1024) {   // 2000 outputs
        int n = i >> 3, k = i & 7;
        float acc = 0.0f;
        const float* srow = &s[n * Rn];
        for (int t = 0; t < Rn; t++) acc += srow[t] * comp_l[t * Kn + k];
        g[i] = acc;
    }
}

// K4: wave-autonomous gather: each wave loads a FULL 512B embedding row per
// instruction (float2/lane), unroll-2 for MLP. 4-wave LDS combine, direct store.
__global__ __launch_bounds__(256) void gather_kernel(const int* __restrict__ node_ids,
                                                     const float* __restrict__ emb,
                                                     const float* __restrict__ a,
                                                     float* __restrict__ partial) {
    int b = blockIdx.x, c = blockIdx.y;
    int lane = threadIdx.x & 63, wv = threadIdx.x >> 6;   // 4 waves
    float acc[18];
#pragma unroll
    for (int k = 0; k < 18; k++) acc[k] = 0.0f;
    const int* nb = node_ids + b * Nn;
    for (int n = c * 4 + wv; n < Nn; n += 2 * CH * 4) {   // nodes n, n + CH*4
        int n2 = n + CH * 4;
        bool has2 = n2 < Nn;
        int nid  = nb[n];
        int nid2 = has2 ? nb[n2] : 0;
        float2 v  = ((const float2*)(emb + (size_t)nid  * Dn))[lane];
        float2 v2 = has2 ? ((const float2*)(emb + (size_t)nid2 * Dn))[lane]
                         : make_float2(0.f, 0.f);
        const float4* ar = (const float4*)(a + ((size_t)b * Nn + n) * Kn);
        float4 a0 = ar[0], a1 = ar[1];
        float w[9] = {a0.x, a0.y, a0.z, a0.w, a1.x, a1.y, a1.z, a1.w, 1.0f};
#pragma unroll
        for (int k = 0; k < 9; k++) { acc[2*k] += w[k] * v.x; acc[2*k+1] += w[k] * v.y; }
        if (has2) {
            const float4* ar2 = (const float4*)(a + ((size_t)b * Nn + n2) * Kn);
            float4 b0 = ar2[0], b1 = ar2[1];
            float w2[9] = {b0.x, b0.y, b0.z, b0.w, b1.x, b1.y, b1.z, b1.w, 1.0f};
#pragma unroll
            for (int k = 0; k < 9; k++) { acc[2*k] += w2[k] * v2.x; acc[2*k+1] += w2[k] * v2.y; }
        }
    }
    __shared__ float red[4 * 9 * Dn];             // 18 KB
#pragma unroll
    for (int k = 0; k < 9; k++) {
        ((float2*)&red[(wv * 9 + k) * Dn])[lane] = make_float2(acc[2*k], acc[2*k+1]);
    }
    __syncthreads();
    float* g = partial + ((size_t)b * CH + c) * 9 * Dn;
    for (int i = threadIdx.x; i < 9 * Dn; i += 256)
        g[i] = red[i] + red[9 * Dn + i] + red[18 * Dn + i] + red[27 * Dn + i];
}

// K5: one block per (graph, matrix m). m<8 -> bases[m] @ t_m ; m==8 -> root @ s.
__global__ __launch_bounds__(256) void matvec_kernel(const float* __restrict__ partial,
                                                     const float* __restrict__ root,
                                                     const float* __restrict__ bases,
                                                     float* __restrict__ gmat) {
    int b = blockIdx.x, m = blockIdx.y;
    int d = threadIdx.x & (Dn - 1), h = threadIdx.x >> 7;
    __shared__ float ts[Dn];
    __shared__ float tsh[2][Dn];
    const float* p = partial + (size_t)b * CH * 9 * Dn + m * Dn + d;
    float sum = 0.0f;
    for (int c = h; c < CH; c += 2) sum += p[(size_t)c * 9 * Dn];
    tsh[h][d] = sum;
    __syncthreads();
    if (h == 0) ts[d] = tsh[0][d] + tsh[1][d];
    __syncthreads();
    const float* M = (m == 8) ? root : bases + (size_t)m * Dn * Dn;
    float g = 0.0f;
    for (int j = h * 64; j < h * 64 + 64; j++) g += ts[j] * M[j * Dn + d];
    __syncthreads();
    tsh[h][d] = g;
    __syncthreads();
    if (h == 0) gmat[((size_t)b * 9 + m) * Dn + d] = tsh[0][d] + tsh[1][d];
}

// K6: sum the 9 matvec outputs, add bias term, L2-normalize.
__global__ __launch_bounds__(128) void norm_kernel(const float* __restrict__ gmat,
                                                   const float* __restrict__ bias,
                                                   float* __restrict__ out) {
    int b = blockIdx.x, d = threadIdx.x;
    float g = (float)Nn * bias[d];
    const float* gb = gmat + (size_t)b * 9 * Dn + d;
#pragma unroll
    for (int m = 0; m < 9; m++) g += gb[m * Dn];
    float ss = g * g;
#pragma unroll
    for (int off = 32; off > 0; off >>= 1) ss += __shfl_down(ss, off, 64);
    __shared__ float s2[2];
    if ((threadIdx.x & 63) == 0) s2[threadIdx.x >> 6] = ss;
    __syncthreads();
    float nrm = sqrtf(s2[0] + s2[1]);
    out[b * Dn + d] = g / fmaxf(nrm, 1e-5f);
}

extern "C" void kernel_launch(void* const* d_in, const int* in_sizes, int n_in,
                              void* d_out, int out_size, void* d_ws, size_t ws_size,
                              hipStream_t stream) {
    const int*   node_ids   = (const int*)d_in[0];
    const int*   edge_index = (const int*)d_in[1];
    const int*   edge_type  = (const int*)d_in[2];
    const float* embedding  = (const float*)d_in[3];
    const float* bases      = (const float*)d_in[4];
    const float* comp       = (const float*)d_in[5];
    const float* root       = (const float*)d_in[6];
    const float* bias       = (const float*)d_in[7];
    float*       out        = (float*)d_out;

    char* w = (char*)d_ws;
    int*   cnt     = (int*)  (w + 0);
    float* inv     = (float*)(w + 9984000);
    float* a       = (float*)(w + 14080000);
    float* partial = (float*)(w + 16128000);
    float* gmat    = (float*)(w + 35004416);

    cnt_kernel   <<<dim3(Bn, SUBS), 1024, 0, stream>>>(edge_index, edge_type, cnt);
    inv_kernel   <<<dim3(Bn, (EQ + 255) / 256), 256, 0, stream>>>(edge_index, edge_type, cnt, inv);
    a_kernel     <<<dim3(Bn, SUBS), 1024, 0, stream>>>(edge_index, edge_type, inv, comp, a);
    gather_kernel<<<dim3(Bn, CH),   256,  0, stream>>>(node_ids, embedding, a, partial);
    matvec_kernel<<<dim3(Bn, 9),    256,  0, stream>>>(partial, root, bases, gmat);
    norm_kernel  <<<Bn, 128, 0, stream>>>(gmat, bias, out);
}